// Round 6
// baseline (472.434 us; speedup 1.0000x reference)
//
#include <hip/hip_runtime.h>
#include <hip/hip_bf16.h>
#include <hip/hip_cooperative_groups.h>

namespace cg = cooperative_groups;

#define NH   32
#define NKVH 8
#define NG   4
#define DD   128
#define HID  4096
#define NQKV 6144
#define NB   32
#define SS   2048
#define SCALE 0.08838834764831845f
#define CHUNK 128
#define NCHUNK 16
#define QSPLIT 8
#define OSPLIT 8

typedef __attribute__((ext_vector_type(4))) float f32x4;
typedef __attribute__((ext_vector_type(8))) short bf16x8;
typedef __attribute__((ext_vector_type(4))) unsigned int u32x4;

// ws float offsets
#define OFF_QKVP  0u          // [8][32][6144]  = 1572864
#define OFF_QR    1572864u    // [32][32][128]  = 131072
#define OFF_KR    1703936u    // [32][8][128]   = 32768
#define OFF_VB    1736704u    // [32][8][128]   = 32768
#define OFF_PART  1769472u    // 256*16*520     = 2129920
#define OFF_ABF   3899392u    // 131072 ushort  = 65536 f32
#define OFF_OPART 3964928u    // [8][32][4096]  = 1048576
#define OFF_CNT   5013504u

static __device__ __forceinline__ unsigned short f2bf(float f) {
    __hip_bfloat16 h = __float2bfloat16(f);
    return __builtin_bit_cast(unsigned short, h);
}

// pack two f32 -> {bf16(a) low, bf16(b) high}, half-ULP bias rounding
static __device__ __forceinline__ unsigned int pack_bf16(float a, float b) {
    unsigned int ua = __builtin_bit_cast(unsigned int, a) + 0x8000u;
    unsigned int ub = __builtin_bit_cast(unsigned int, b) + 0x8000u;
    return __builtin_amdgcn_perm(ub, ua, 0x07060302u);
}

// ======================= device phase bodies (shared) =======================

// qkv GEMM job: A = hs (f32, converted in-reg). job = jt + 384*ks.
static __device__ __forceinline__ void qkv_gemm_job(
    int job, int wave, int lane, int l16, int kgrp,
    const float* __restrict__ hs, const float* __restrict__ w_qkv,
    float* __restrict__ qkv_part, f32x4 (*redsm)[2][64]) {
    int jt = job % 384, ks = job / 384;
    int j0 = jt * 16;
    const int K = HID, Kslice = HID / QSPLIT;          // 512
    int kbeg = ks * Kslice + wave * (Kslice / 4);      // 128 per wave
    f32x4 acc0 = {0.f,0.f,0.f,0.f}, acc1 = {0.f,0.f,0.f,0.f};
    const float* ar0 = hs + (size_t)l16 * K;
    const float* ar1 = hs + (size_t)(16 + l16) * K;
    const float* wr  = w_qkv + (size_t)(j0 + l16) * K;
#pragma unroll
    for (int k = kbeg; k < kbeg + Kslice / 4; k += 32) {   // 4 iters
        int kk = k + kgrp * 8;
        f32x4 a00 = *(const f32x4*)(ar0 + kk), a01 = *(const f32x4*)(ar0 + kk + 4);
        f32x4 a10 = *(const f32x4*)(ar1 + kk), a11 = *(const f32x4*)(ar1 + kk + 4);
        f32x4 w0  = *(const f32x4*)(wr  + kk), w1  = *(const f32x4*)(wr  + kk + 4);
        u32x4 pa0, pa1, pw;
        pa0[0] = pack_bf16(a00[0], a00[1]); pa0[1] = pack_bf16(a00[2], a00[3]);
        pa0[2] = pack_bf16(a01[0], a01[1]); pa0[3] = pack_bf16(a01[2], a01[3]);
        pa1[0] = pack_bf16(a10[0], a10[1]); pa1[1] = pack_bf16(a10[2], a10[3]);
        pa1[2] = pack_bf16(a11[0], a11[1]); pa1[3] = pack_bf16(a11[2], a11[3]);
        pw[0]  = pack_bf16(w0[0],  w0[1]);  pw[1]  = pack_bf16(w0[2],  w0[3]);
        pw[2]  = pack_bf16(w1[0],  w1[1]);  pw[3]  = pack_bf16(w1[2],  w1[3]);
        bf16x8 bw = __builtin_bit_cast(bf16x8, pw);
        acc0 = __builtin_amdgcn_mfma_f32_16x16x32_bf16(__builtin_bit_cast(bf16x8, pa0), bw, acc0, 0, 0, 0);
        acc1 = __builtin_amdgcn_mfma_f32_16x16x32_bf16(__builtin_bit_cast(bf16x8, pa1), bw, acc1, 0, 0, 0);
    }
    redsm[wave][0][lane] = acc0;
    redsm[wave][1][lane] = acc1;
    __syncthreads();
    if (wave == 0) {
        for (int t = 0; t < 2; ++t) {
            f32x4 s = redsm[0][t][lane];
            s += redsm[1][t][lane]; s += redsm[2][t][lane]; s += redsm[3][t][lane];
            for (int r = 0; r < 4; ++r)
                qkv_part[((size_t)ks * 32 + t * 16 + kgrp * 4 + r) * NQKV + j0 + l16] = s[r];
        }
    }
    __syncthreads();
}

// o GEMM job: A = attn_bf (bf16). job = jt + 256*ks.
static __device__ __forceinline__ void o_gemm_job(
    int job, int wave, int lane, int l16, int kgrp,
    const unsigned short* __restrict__ attn_bf, const float* __restrict__ w_o,
    float* __restrict__ o_part, f32x4 (*redsm)[2][64]) {
    int jt = job & 255, ks = job >> 8;
    int j0 = jt * 16;
    const int K = HID, Kslice = HID / OSPLIT;    // 512
    int kbeg = ks * Kslice + wave * (Kslice / 4);
    f32x4 acc0 = {0.f,0.f,0.f,0.f}, acc1 = {0.f,0.f,0.f,0.f};
    const unsigned short* ar0 = attn_bf + (size_t)l16 * K;
    const unsigned short* ar1 = attn_bf + (size_t)(16 + l16) * K;
    const float* wr = w_o + (size_t)(j0 + l16) * K;
#pragma unroll
    for (int k = kbeg; k < kbeg + Kslice / 4; k += 32) {   // 4 iters
        int kk = k + kgrp * 8;
        bf16x8 a0 = *(const bf16x8*)(ar0 + kk);
        bf16x8 a1 = *(const bf16x8*)(ar1 + kk);
        f32x4 w0 = *(const f32x4*)(wr + kk), w1 = *(const f32x4*)(wr + kk + 4);
        u32x4 pw;
        pw[0] = pack_bf16(w0[0], w0[1]); pw[1] = pack_bf16(w0[2], w0[3]);
        pw[2] = pack_bf16(w1[0], w1[1]); pw[3] = pack_bf16(w1[2], w1[3]);
        bf16x8 bw = __builtin_bit_cast(bf16x8, pw);
        acc0 = __builtin_amdgcn_mfma_f32_16x16x32_bf16(a0, bw, acc0, 0, 0, 0);
        acc1 = __builtin_amdgcn_mfma_f32_16x16x32_bf16(a1, bw, acc1, 0, 0, 0);
    }
    redsm[wave][0][lane] = acc0;
    redsm[wave][1][lane] = acc1;
    __syncthreads();
    if (wave == 0) {
        for (int t = 0; t < 2; ++t) {
            f32x4 s = redsm[0][t][lane];
            s += redsm[1][t][lane]; s += redsm[2][t][lane]; s += redsm[3][t][lane];
            for (int r = 0; r < 4; ++r)
                o_part[((size_t)ks * 32 + t * 16 + kgrp * 4 + r) * HID + j0 + l16] = s[r];
        }
    }
    __syncthreads();
}

// rope/reduce element idx in [0, 114688)
static __device__ __forceinline__ void rope_elem(
    int idx, const float* __restrict__ qkv_part, const int* __restrict__ positions,
    float* __restrict__ q_rope, float* __restrict__ k_rope, float* __restrict__ vbuf) {
    const int NROPE = NB * 40 * 64;    // 81920
    if (idx < NROPE) {
        int i = idx & 63, head = (idx >> 6) % 40, b = idx / (64 * 40);
        size_t base = (size_t)b * NQKV + head * DD;
        float x1 = 0.f, x2 = 0.f;
#pragma unroll
        for (int p = 0; p < QSPLIT; ++p) {
            x1 += qkv_part[(size_t)p * 32 * NQKV + base + i];
            x2 += qkv_part[(size_t)p * 32 * NQKV + base + i + 64];
        }
        float pos = (float)positions[b];
        float inv = exp2f(-(float)i * 0.20762050593046f);   // theta^(-i/64)
        float fr = pos * inv, s, c;
        sincosf(fr, &s, &c);
        float o1 = x1 * c - x2 * s, o2 = x2 * c + x1 * s;
        if (head < NH) {
            float* d = q_rope + ((size_t)b * NH + head) * DD;
            d[i] = o1; d[i + 64] = o2;
        } else {
            float* d = k_rope + ((size_t)b * NKVH + (head - NH)) * DD;
            d[i] = o1; d[i + 64] = o2;
        }
    } else {
        int j = idx - NROPE;
        size_t base = (size_t)(j >> 10) * NQKV + (NH + NKVH) * DD + (j & 1023);
        float v = 0.f;
#pragma unroll
        for (int p = 0; p < QSPLIT; ++p) v += qkv_part[(size_t)p * 32 * NQKV + base];
        vbuf[j] = v;
    }
}

// attention chunk job
static __device__ __forceinline__ void attn_job(
    int job, int tid, int wave, int lane, int l16,
    const float* __restrict__ k_cache, const float* __restrict__ v_cache,
    const float* __restrict__ q_rope, const float* __restrict__ k_rope,
    const float* __restrict__ vbuf, const int* __restrict__ positions,
    float* __restrict__ part,
    float (*sc)[CHUNK], float* mg, float* lg, f32x4 (*red2)[4][32]) {
    int bk = job & 255, c = job >> 8;
    int b = bk >> 3, kvh = bk & 7;
    int pos = positions[b];
    int s0 = c * CHUNK;
    float* mypart = part + ((size_t)bk * NCHUNK + c) * 520;
    if (s0 > pos) {
        if (tid < 4) { mypart[tid] = -__builtin_inff(); mypart[4 + tid] = 0.f; }
        return;
    }
    int nvalid = min(pos + 1 - s0, CHUNK);
    int rsub = lane >> 4;

    for (int i = tid; i < 4 * CHUNK; i += 256) ((float*)sc)[i] = -__builtin_inff();
    __syncthreads();

    float qf[4][8];
    const float* qbase = q_rope + ((size_t)b * NH + kvh * NG) * DD;
#pragma unroll
    for (int g = 0; g < 4; ++g)
#pragma unroll
        for (int e = 0; e < 8; ++e)
            qf[g][e] = qbase[g * DD + l16 * 8 + e];

    const float* kcb = k_cache + ((size_t)b * SS * NKVH + kvh) * DD;
    const float* krp = k_rope + ((size_t)b * NKVH + kvh) * DD;

    if (nvalid == CHUNK) {
#pragma unroll
        for (int it = 0; it < CHUNK / 16; ++it) {
            int row = it * 16 + wave * 4 + rsub;
            int s = s0 + row;
            const float* krow = (s == pos) ? krp : (kcb + (size_t)s * (NKVH * DD));
            f32x4 k0 = *(const f32x4*)(krow + l16 * 8);
            f32x4 k1 = *(const f32x4*)(krow + l16 * 8 + 4);
            float dots[4];
#pragma unroll
            for (int g = 0; g < 4; ++g)
                dots[g] = qf[g][0]*k0[0] + qf[g][1]*k0[1] + qf[g][2]*k0[2] + qf[g][3]*k0[3]
                        + qf[g][4]*k1[0] + qf[g][5]*k1[1] + qf[g][6]*k1[2] + qf[g][7]*k1[3];
#pragma unroll
            for (int m = 1; m < 16; m <<= 1)
#pragma unroll
                for (int g = 0; g < 4; ++g)
                    dots[g] += __shfl_xor(dots[g], m, 64);
            if (l16 == 0)
#pragma unroll
                for (int g = 0; g < 4; ++g) sc[g][row] = dots[g] * SCALE;
        }
    } else {
#pragma unroll 2
        for (int it = 0; it < CHUNK / 16; ++it) {
            int row = it * 16 + wave * 4 + rsub;
            if (row >= nvalid) continue;
            int s = s0 + row;
            const float* krow = (s == pos) ? krp : (kcb + (size_t)s * (NKVH * DD));
            f32x4 k0 = *(const f32x4*)(krow + l16 * 8);
            f32x4 k1 = *(const f32x4*)(krow + l16 * 8 + 4);
            float dots[4];
#pragma unroll
            for (int g = 0; g < 4; ++g)
                dots[g] = qf[g][0]*k0[0] + qf[g][1]*k0[1] + qf[g][2]*k0[2] + qf[g][3]*k0[3]
                        + qf[g][4]*k1[0] + qf[g][5]*k1[1] + qf[g][6]*k1[2] + qf[g][7]*k1[3];
#pragma unroll
            for (int m = 1; m < 16; m <<= 1)
#pragma unroll
                for (int g = 0; g < 4; ++g)
                    dots[g] += __shfl_xor(dots[g], m, 64);
            if (l16 == 0)
#pragma unroll
                for (int g = 0; g < 4; ++g) sc[g][row] = dots[g] * SCALE;
        }
    }
    __syncthreads();

    {   // softmax partial: wave g handles group g (2 vals/lane)
        int g = wave;
        float v0 = sc[g][lane], v1 = sc[g][lane + 64];
        float m = fmaxf(v0, v1);
#pragma unroll
        for (int msk = 1; msk < 64; msk <<= 1) m = fmaxf(m, __shfl_xor(m, msk, 64));
        float p0 = expf(v0 - m), p1 = expf(v1 - m);
        float l = p0 + p1;
#pragma unroll
        for (int msk = 1; msk < 64; msk <<= 1) l += __shfl_xor(l, msk, 64);
        sc[g][lane] = p0; sc[g][lane + 64] = p1;
        if (lane == 0) { mg[g] = m; lg[g] = l; }
    }
    __syncthreads();

    int sid = tid >> 5, l32 = tid & 31;
    f32x4 acc[4] = {{0.f,0.f,0.f,0.f},{0.f,0.f,0.f,0.f},{0.f,0.f,0.f,0.f},{0.f,0.f,0.f,0.f}};
    const float* vcb = v_cache + ((size_t)b * SS * NKVH + kvh) * DD;
    const float* vrp = vbuf + ((size_t)b * NKVH + kvh) * DD;
    if (nvalid == CHUNK) {
#pragma unroll 4
        for (int row = sid; row < CHUNK; row += 8) {
            int s = s0 + row;
            const float* vrow = (s == pos) ? vrp : (vcb + (size_t)s * (NKVH * DD));
            f32x4 v4 = *(const f32x4*)(vrow + l32 * 4);
#pragma unroll
            for (int g = 0; g < 4; ++g) acc[g] += sc[g][row] * v4;
        }
    } else {
#pragma unroll 2
        for (int row = sid; row < nvalid; row += 8) {
            int s = s0 + row;
            const float* vrow = (s == pos) ? vrp : (vcb + (size_t)s * (NKVH * DD));
            f32x4 v4 = *(const f32x4*)(vrow + l32 * 4);
#pragma unroll
            for (int g = 0; g < 4; ++g) acc[g] += sc[g][row] * v4;
        }
    }
#pragma unroll
    for (int g = 0; g < 4; ++g) red2[sid][g][l32] = acc[g];
    __syncthreads();
    if (tid < 128) {
        int g = tid >> 5, l = tid & 31;
        f32x4 s = red2[0][g][l];
#pragma unroll
        for (int w = 1; w < 8; ++w) s += red2[w][g][l];
        *(f32x4*)(mypart + 8 + g * DD + l * 4) = s;
        if (l == 0) { mypart[g] = mg[g]; mypart[4 + g] = lg[g]; }
    }
}

// combine job (bk), threads 0..127
static __device__ __forceinline__ void combine_job(
    int bk, int tid, const float* __restrict__ part, unsigned short* __restrict__ attn_bf) {
    int b = bk >> 3, kvh = bk & 7;
    const float* p0 = part + (size_t)bk * NCHUNK * 520;
    int g = tid >> 5, l32 = tid & 31;
    float M = -__builtin_inff();
#pragma unroll
    for (int c = 0; c < NCHUNK; ++c) {
        float lcv = p0[c * 520 + 4 + g];
        float mcv = p0[c * 520 + g];
        if (lcv > 0.f && mcv > M) M = mcv;
    }
    float L = 0.f;
    f32x4 acc = {0.f, 0.f, 0.f, 0.f};
#pragma unroll
    for (int c = 0; c < NCHUNK; ++c) {
        float lcv = p0[c * 520 + 4 + g];
        float mcv = p0[c * 520 + g];
        if (lcv > 0.f) {
            float wgt = expf(mcv - M);
            L += lcv * wgt;
            f32x4 a = *(const f32x4*)(p0 + c * 520 + 8 + g * DD + l32 * 4);
            acc += wgt * a;
        }
    }
    float inv = 1.0f / L;
    unsigned short* o = attn_bf + (((size_t)b * NH) + kvh * NG + g) * DD + l32 * 4;
#pragma unroll
    for (int r = 0; r < 4; ++r) o[r] = f2bf(acc[r] * inv);
}

static __device__ __forceinline__ void reduce_o_elem(
    int idx, const float* __restrict__ o_part, float* __restrict__ out) {
    const f32x4* p = (const f32x4*)o_part;
    f32x4 s = p[idx];
#pragma unroll
    for (int k = 1; k < OSPLIT; ++k) s += p[idx + k * 32768];
    ((f32x4*)out)[idx] = s;
}

// ============================ cooperative mega ============================
__global__ __launch_bounds__(256) void mega(
    const float* __restrict__ hs, const float* __restrict__ w_qkv,
    const float* __restrict__ w_o, const float* __restrict__ k_cache,
    const float* __restrict__ v_cache, const int* __restrict__ positions,
    float* __restrict__ out, float* __restrict__ wsf)
{
    cg::grid_group grid = cg::this_grid();
    const int bid = blockIdx.x, tid = threadIdx.x;
    const int wave = tid >> 6, lane = tid & 63, l16 = lane & 15, kgrp = lane >> 4;
    const int nb = gridDim.x;

    float* qkv_part = wsf + OFF_QKVP;
    float* q_rope   = wsf + OFF_QR;
    float* k_rope   = wsf + OFF_KR;
    float* vbuf     = wsf + OFF_VB;
    float* part     = wsf + OFF_PART;
    unsigned short* attn_bf = (unsigned short*)(wsf + OFF_ABF);
    float* o_part   = wsf + OFF_OPART;
    unsigned int* cnt = (unsigned int*)(wsf + OFF_CNT);

    __shared__ f32x4 redsm[4][2][64];
    __shared__ float sc[4][CHUNK];
    __shared__ float mg[4], lg[4];
    __shared__ f32x4 red2[8][4][32];
    __shared__ int jobsm;

    if (bid == 0 && tid == 0) *cnt = 0u;

    // P1: qkv GEMM — 3072 jobs
    for (int job = bid; job < 384 * QSPLIT; job += nb)
        qkv_gemm_job(job, wave, lane, l16, kgrp, hs, w_qkv, qkv_part, redsm);
    __threadfence();
    grid.sync();

    // P2: reduce + rope + v extract — 114688 elems
    for (int idx = bid * 256 + tid; idx < NB * 40 * 64 + NB * NKVH * DD; idx += nb * 256)
        rope_elem(idx, qkv_part, positions, q_rope, k_rope, vbuf);
    __threadfence();
    grid.sync();

    // P3: attention partials — work-stealing over 4096 jobs
    for (;;) {
        __syncthreads();
        if (tid == 0) jobsm = (int)atomicAdd(cnt, 1u);
        __syncthreads();
        int job = jobsm;
        if (job >= NB * NKVH * NCHUNK) break;
        attn_job(job, tid, wave, lane, l16, k_cache, v_cache, q_rope, k_rope,
                 vbuf, positions, part, sc, mg, lg, red2);
    }
    __threadfence();
    grid.sync();

    // P4: combine — 256 jobs
    for (int bk = bid; bk < NB * NKVH; bk += nb)
        if (tid < 128) combine_job(bk, tid, part, attn_bf);
    __threadfence();
    grid.sync();

    // P5: o GEMM — 2048 jobs
    for (int job = bid; job < 256 * OSPLIT; job += nb)
        o_gemm_job(job, wave, lane, l16, kgrp, attn_bf, w_o, o_part, redsm);
    __threadfence();
    grid.sync();

    // P6: reduce o partials — 32768 f32x4
    for (int idx = bid * 256 + tid; idx < 32768; idx += nb * 256)
        reduce_o_elem(idx, o_part, out);
}

// ============================ fallback kernels ============================
__global__ __launch_bounds__(256) void fb_qkv_gemm(
    const float* __restrict__ hs, const float* __restrict__ w_qkv,
    float* __restrict__ qkv_part) {
    __shared__ f32x4 redsm[4][2][64];
    int tid = threadIdx.x;
    qkv_gemm_job(blockIdx.x + 384 * blockIdx.y, tid >> 6, tid & 63, tid & 15,
                 (tid & 63) >> 4, hs, w_qkv, qkv_part, redsm);
}

__global__ __launch_bounds__(256) void fb_rope(
    const float* __restrict__ qkv_part, const int* __restrict__ positions,
    float* __restrict__ q_rope, float* __restrict__ k_rope, float* __restrict__ vbuf) {
    int idx = blockIdx.x * 256 + threadIdx.x;
    if (idx < NB * 40 * 64 + NB * NKVH * DD)
        rope_elem(idx, qkv_part, positions, q_rope, k_rope, vbuf);
}

__global__ __launch_bounds__(256) void fb_attn(
    const float* __restrict__ k_cache, const float* __restrict__ v_cache,
    const float* __restrict__ q_rope, const float* __restrict__ k_rope,
    const float* __restrict__ vbuf, const int* __restrict__ positions,
    float* __restrict__ part) {
    __shared__ float sc[4][CHUNK];
    __shared__ float mg[4], lg[4];
    __shared__ f32x4 red2[8][4][32];
    int tid = threadIdx.x;
    attn_job(blockIdx.x + 256 * blockIdx.y, tid, tid >> 6, tid & 63, tid & 15,
             k_cache, v_cache, q_rope, k_rope, vbuf, positions, part, sc, mg, lg, red2);
}

__global__ __launch_bounds__(128) void fb_combine(
    const float* __restrict__ part, unsigned short* __restrict__ attn_bf) {
    combine_job(blockIdx.x, threadIdx.x, part, attn_bf);
}

__global__ __launch_bounds__(256) void fb_o_gemm(
    const unsigned short* __restrict__ attn_bf, const float* __restrict__ w_o,
    float* __restrict__ o_part) {
    __shared__ f32x4 redsm[4][2][64];
    int tid = threadIdx.x;
    o_gemm_job(blockIdx.x + 256 * blockIdx.y, tid >> 6, tid & 63, tid & 15,
               (tid & 63) >> 4, attn_bf, w_o, o_part, redsm);
}

__global__ __launch_bounds__(256) void fb_reduce_o(
    const float* __restrict__ o_part, float* __restrict__ out) {
    reduce_o_elem(blockIdx.x * 256 + threadIdx.x, o_part, out);
}

extern "C" void kernel_launch(void* const* d_in, const int* in_sizes, int n_in,
                              void* d_out, int out_size, void* d_ws, size_t ws_size,
                              hipStream_t stream) {
    const float* hs      = (const float*)d_in[0];
    const float* w_qkv   = (const float*)d_in[1];
    const float* w_o     = (const float*)d_in[2];
    const float* k_cache = (const float*)d_in[3];
    const float* v_cache = (const float*)d_in[4];
    const int*   positions = (const int*)d_in[5];
    float* out = (float*)d_out;
    float* wsf = (float*)d_ws;

    float* p_qkv_part = wsf + OFF_QKVP;
    float* p_q_rope   = wsf + OFF_QR;
    float* p_k_rope   = wsf + OFF_KR;
    float* p_vbuf     = wsf + OFF_VB;
    float* p_part     = wsf + OFF_PART;
    unsigned short* p_attn_bf = (unsigned short*)(wsf + OFF_ABF);
    float* p_o_part   = wsf + OFF_OPART;

    int maxb = 0;
    hipError_t qe = hipOccupancyMaxActiveBlocksPerMultiprocessor(
        &maxb, (const void*)mega, 256, 0);
    hipError_t le = hipErrorUnknown;
    if (qe == hipSuccess && maxb > 0) {
        int nblk = maxb * 256;            // 256 CUs
        if (nblk > 1024) nblk = 1024;
        const float* a0 = hs; const float* a1 = w_qkv; const float* a2 = w_o;
        const float* a3 = k_cache; const float* a4 = v_cache;
        const int* a5 = positions; float* a6 = out; float* a7 = wsf;
        void* args[8] = { &a0, &a1, &a2, &a3, &a4, &a5, &a6, &a7 };
        le = hipLaunchCooperativeKernel((const void*)mega, dim3(nblk), dim3(256),
                                        args, 0, stream);
    }
    if (le != hipSuccess) {
        (void)hipGetLastError();   // clear error state, use fallback path
        hipLaunchKernelGGL(fb_qkv_gemm, dim3(384, QSPLIT), dim3(256), 0, stream,
                           hs, w_qkv, p_qkv_part);
        hipLaunchKernelGGL(fb_rope, dim3(448), dim3(256), 0, stream,
                           p_qkv_part, positions, p_q_rope, p_k_rope, p_vbuf);
        hipLaunchKernelGGL(fb_attn, dim3(256, NCHUNK), dim3(256), 0, stream,
                           k_cache, v_cache, p_q_rope, p_k_rope, p_vbuf, positions, p_part);
        hipLaunchKernelGGL(fb_combine, dim3(NB * NKVH), dim3(128), 0, stream, p_part, p_attn_bf);
        hipLaunchKernelGGL(fb_o_gemm, dim3(256, OSPLIT), dim3(256), 0, stream,
                           p_attn_bf, w_o, p_o_part);
        hipLaunchKernelGGL(fb_reduce_o, dim3(128), dim3(256), 0, stream, p_o_part, out);
    }
}

// Round 7
// 128.054 us; speedup vs baseline: 3.6893x; 3.6893x over previous
//
#include <hip/hip_runtime.h>
#include <hip/hip_bf16.h>

#define NH   32
#define NKVH 8
#define NG   4
#define DD   128
#define HID  4096
#define NQKV 6144
#define NB   32
#define SS   2048
#define SCALE 0.08838834764831845f
#define CHUNK 128
#define NCHUNK 16
#define QSPLIT 8
#define OSPLIT 16

typedef __attribute__((ext_vector_type(4))) float f32x4;
typedef __attribute__((ext_vector_type(8))) short bf16x8;
typedef __attribute__((ext_vector_type(4))) unsigned int u32x4;

// ws float offsets
#define OFF_QKVP  0u          // [8][32][6144]   = 1572864
#define OFF_QR    1572864u    // [32][32][128]   = 131072
#define OFF_KR    1703936u    // [32][8][128]    = 32768
#define OFF_VB    1736704u    // [32][8][128]    = 32768
#define OFF_PART  1769472u    // 256*16*520      = 2129920
#define OFF_ABF   3899392u    // 131072 ushort   = 65536 f32
#define OFF_OPART 3964928u    // [16][32][4096]  = 2097152

static __device__ __forceinline__ unsigned short f2bf(float f) {
    __hip_bfloat16 h = __float2bfloat16(f);
    return __builtin_bit_cast(unsigned short, h);
}

// pack two f32 -> {bf16(a) low, bf16(b) high}, half-ULP bias rounding
static __device__ __forceinline__ unsigned int pack_bf16(float a, float b) {
    unsigned int ua = __builtin_bit_cast(unsigned int, a) + 0x8000u;
    unsigned int ub = __builtin_bit_cast(unsigned int, b) + 0x8000u;
    return __builtin_amdgcn_perm(ub, ua, 0x07060302u);
}

// ---------------- qkv GEMM: barrier-free, wave-owned 16-col tiles ----------------
// grid (96, QSPLIT), block 256. Wave w owns cols [(bid.x*4+w)*16, +16), K-slice bid.y.
__global__ __launch_bounds__(256) void g_qkv(
    const float* __restrict__ hs, const float* __restrict__ w_qkv,
    float* __restrict__ qkv_part) {
    int tid = threadIdx.x;
    int wave = tid >> 6, lane = tid & 63, l16 = lane & 15, kgrp = lane >> 4;
    int j0 = (blockIdx.x * 4 + wave) * 16;
    int ks = blockIdx.y;
    const int K = HID, Kslice = HID / QSPLIT;   // 512
    int kbeg = ks * Kslice;

    f32x4 acc0 = {0.f,0.f,0.f,0.f}, acc1 = {0.f,0.f,0.f,0.f};
    const float* ar0 = hs + (size_t)l16 * K;
    const float* ar1 = hs + (size_t)(16 + l16) * K;
    const float* wr  = w_qkv + (size_t)(j0 + l16) * K;

#pragma unroll 4
    for (int k = kbeg; k < kbeg + Kslice; k += 32) {   // 16 iters
        int kk = k + kgrp * 8;
        f32x4 a00 = *(const f32x4*)(ar0 + kk), a01 = *(const f32x4*)(ar0 + kk + 4);
        f32x4 a10 = *(const f32x4*)(ar1 + kk), a11 = *(const f32x4*)(ar1 + kk + 4);
        f32x4 w0  = *(const f32x4*)(wr  + kk), w1  = *(const f32x4*)(wr  + kk + 4);
        u32x4 pa0, pa1, pw;
        pa0[0] = pack_bf16(a00[0], a00[1]); pa0[1] = pack_bf16(a00[2], a00[3]);
        pa0[2] = pack_bf16(a01[0], a01[1]); pa0[3] = pack_bf16(a01[2], a01[3]);
        pa1[0] = pack_bf16(a10[0], a10[1]); pa1[1] = pack_bf16(a10[2], a10[3]);
        pa1[2] = pack_bf16(a11[0], a11[1]); pa1[3] = pack_bf16(a11[2], a11[3]);
        pw[0]  = pack_bf16(w0[0],  w0[1]);  pw[1]  = pack_bf16(w0[2],  w0[3]);
        pw[2]  = pack_bf16(w1[0],  w1[1]);  pw[3]  = pack_bf16(w1[2],  w1[3]);
        bf16x8 bw = __builtin_bit_cast(bf16x8, pw);
        acc0 = __builtin_amdgcn_mfma_f32_16x16x32_bf16(__builtin_bit_cast(bf16x8, pa0), bw, acc0, 0, 0, 0);
        acc1 = __builtin_amdgcn_mfma_f32_16x16x32_bf16(__builtin_bit_cast(bf16x8, pa1), bw, acc1, 0, 0, 0);
    }
    float* dst = qkv_part + (size_t)ks * 32 * NQKV + j0 + l16;
#pragma unroll
    for (int r = 0; r < 4; ++r) {
        dst[(size_t)(kgrp * 4 + r) * NQKV] = acc0[r];
        dst[(size_t)(16 + kgrp * 4 + r) * NQKV] = acc1[r];
    }
}

// ---------------- reduce qkv partials + RoPE + v extract ----------------
__global__ __launch_bounds__(256) void g_rope(
    const float* __restrict__ qkv_part, const int* __restrict__ positions,
    float* __restrict__ q_rope, float* __restrict__ k_rope, float* __restrict__ vbuf) {
    int idx = blockIdx.x * 256 + threadIdx.x;
    const int NROPE = NB * 40 * 64;    // 81920
    const int NV = NB * NKVH * DD;     // 32768
    if (idx < NROPE) {
        int i = idx & 63, head = (idx >> 6) % 40, b = idx / (64 * 40);
        size_t base = (size_t)b * NQKV + head * DD;
        float x1 = 0.f, x2 = 0.f;
#pragma unroll
        for (int p = 0; p < QSPLIT; ++p) {
            x1 += qkv_part[(size_t)p * 32 * NQKV + base + i];
            x2 += qkv_part[(size_t)p * 32 * NQKV + base + i + 64];
        }
        float pos = (float)positions[b];
        float inv = exp2f(-(float)i * 0.20762050593046f);   // theta^(-i/64)
        float fr = pos * inv, s, c;
        sincosf(fr, &s, &c);
        float o1 = x1 * c - x2 * s, o2 = x2 * c + x1 * s;
        if (head < NH) {
            float* d = q_rope + ((size_t)b * NH + head) * DD;
            d[i] = o1; d[i + 64] = o2;
        } else {
            float* d = k_rope + ((size_t)b * NKVH + (head - NH)) * DD;
            d[i] = o1; d[i + 64] = o2;
        }
    } else if (idx < NROPE + NV) {
        int j = idx - NROPE;
        size_t base = (size_t)(j >> 10) * NQKV + (NH + NKVH) * DD + (j & 1023);
        float v = 0.f;
#pragma unroll
        for (int p = 0; p < QSPLIT; ++p) v += qkv_part[(size_t)p * 32 * NQKV + base];
        vbuf[j] = v;
    }
}

// ---------------- attention partial (flash-decode, split-S) ----------------
__global__ __launch_bounds__(256) void g_attn(
    const float* __restrict__ k_cache, const float* __restrict__ v_cache,
    const float* __restrict__ q_rope, const float* __restrict__ k_rope,
    const float* __restrict__ vbuf, const int* __restrict__ positions,
    float* __restrict__ part) {
    int bk = blockIdx.x;
    int c = blockIdx.y;
    int b = bk >> 3, kvh = bk & 7;
    int pos = positions[b];
    int s0 = c * CHUNK;
    float* mypart = part + ((size_t)bk * NCHUNK + c) * 520;
    int tid = threadIdx.x;
    if (s0 > pos) {
        if (tid < 4) { mypart[tid] = -__builtin_inff(); mypart[4 + tid] = 0.f; }
        return;
    }
    int nvalid = min(pos + 1 - s0, CHUNK);

    __shared__ float sc[4][CHUNK];
    __shared__ float mg[4], lg[4];
    __shared__ f32x4 red2[8][4][32];

    int wave = tid >> 6, lane = tid & 63, l16 = lane & 15, rsub = lane >> 4;

    for (int i = tid; i < 4 * CHUNK; i += 256) ((float*)sc)[i] = -__builtin_inff();
    __syncthreads();

    float qf[4][8];
    const float* qbase = q_rope + ((size_t)b * NH + kvh * NG) * DD;
#pragma unroll
    for (int g = 0; g < 4; ++g)
#pragma unroll
        for (int e = 0; e < 8; ++e)
            qf[g][e] = qbase[g * DD + l16 * 8 + e];

    const float* kcb = k_cache + ((size_t)b * SS * NKVH + kvh) * DD;
    const float* krp = k_rope + ((size_t)b * NKVH + kvh) * DD;

    if (nvalid == CHUNK) {
#pragma unroll
        for (int it = 0; it < CHUNK / 16; ++it) {
            int row = it * 16 + wave * 4 + rsub;
            int s = s0 + row;
            const float* krow = (s == pos) ? krp : (kcb + (size_t)s * (NKVH * DD));
            f32x4 k0 = *(const f32x4*)(krow + l16 * 8);
            f32x4 k1 = *(const f32x4*)(krow + l16 * 8 + 4);
            float dots[4];
#pragma unroll
            for (int g = 0; g < 4; ++g)
                dots[g] = qf[g][0]*k0[0] + qf[g][1]*k0[1] + qf[g][2]*k0[2] + qf[g][3]*k0[3]
                        + qf[g][4]*k1[0] + qf[g][5]*k1[1] + qf[g][6]*k1[2] + qf[g][7]*k1[3];
#pragma unroll
            for (int m = 1; m < 16; m <<= 1)
#pragma unroll
                for (int g = 0; g < 4; ++g)
                    dots[g] += __shfl_xor(dots[g], m, 64);
            if (l16 == 0)
#pragma unroll
                for (int g = 0; g < 4; ++g) sc[g][row] = dots[g] * SCALE;
        }
    } else {
#pragma unroll 2
        for (int it = 0; it < CHUNK / 16; ++it) {
            int row = it * 16 + wave * 4 + rsub;
            if (row >= nvalid) continue;
            int s = s0 + row;
            const float* krow = (s == pos) ? krp : (kcb + (size_t)s * (NKVH * DD));
            f32x4 k0 = *(const f32x4*)(krow + l16 * 8);
            f32x4 k1 = *(const f32x4*)(krow + l16 * 8 + 4);
            float dots[4];
#pragma unroll
            for (int g = 0; g < 4; ++g)
                dots[g] = qf[g][0]*k0[0] + qf[g][1]*k0[1] + qf[g][2]*k0[2] + qf[g][3]*k0[3]
                        + qf[g][4]*k1[0] + qf[g][5]*k1[1] + qf[g][6]*k1[2] + qf[g][7]*k1[3];
#pragma unroll
            for (int m = 1; m < 16; m <<= 1)
#pragma unroll
                for (int g = 0; g < 4; ++g)
                    dots[g] += __shfl_xor(dots[g], m, 64);
            if (l16 == 0)
#pragma unroll
                for (int g = 0; g < 4; ++g) sc[g][row] = dots[g] * SCALE;
        }
    }
    __syncthreads();

    {   // softmax partial: wave g handles group g (2 vals/lane)
        int g = wave;
        float v0 = sc[g][lane], v1 = sc[g][lane + 64];
        float m = fmaxf(v0, v1);
#pragma unroll
        for (int msk = 1; msk < 64; msk <<= 1) m = fmaxf(m, __shfl_xor(m, msk, 64));
        float p0 = expf(v0 - m), p1 = expf(v1 - m);
        float l = p0 + p1;
#pragma unroll
        for (int msk = 1; msk < 64; msk <<= 1) l += __shfl_xor(l, msk, 64);
        sc[g][lane] = p0; sc[g][lane + 64] = p1;
        if (lane == 0) { mg[g] = m; lg[g] = l; }
    }
    __syncthreads();

    int sid = tid >> 5, l32 = tid & 31;
    f32x4 acc[4] = {{0.f,0.f,0.f,0.f},{0.f,0.f,0.f,0.f},{0.f,0.f,0.f,0.f},{0.f,0.f,0.f,0.f}};
    const float* vcb = v_cache + ((size_t)b * SS * NKVH + kvh) * DD;
    const float* vrp = vbuf + ((size_t)b * NKVH + kvh) * DD;
    if (nvalid == CHUNK) {
#pragma unroll 4
        for (int row = sid; row < CHUNK; row += 8) {
            int s = s0 + row;
            const float* vrow = (s == pos) ? vrp : (vcb + (size_t)s * (NKVH * DD));
            f32x4 v4 = *(const f32x4*)(vrow + l32 * 4);
#pragma unroll
            for (int g = 0; g < 4; ++g) acc[g] += sc[g][row] * v4;
        }
    } else {
#pragma unroll 2
        for (int row = sid; row < nvalid; row += 8) {
            int s = s0 + row;
            const float* vrow = (s == pos) ? vrp : (vcb + (size_t)s * (NKVH * DD));
            f32x4 v4 = *(const f32x4*)(vrow + l32 * 4);
#pragma unroll
            for (int g = 0; g < 4; ++g) acc[g] += sc[g][row] * v4;
        }
    }
#pragma unroll
    for (int g = 0; g < 4; ++g) red2[sid][g][l32] = acc[g];
    __syncthreads();
    if (tid < 128) {
        int g = tid >> 5, l = tid & 31;
        f32x4 s = red2[0][g][l];
#pragma unroll
        for (int w = 1; w < 8; ++w) s += red2[w][g][l];
        *(f32x4*)(mypart + 8 + g * DD + l * 4) = s;
        if (l == 0) { mypart[g] = mg[g]; mypart[4 + g] = lg[g]; }
    }
}

// ---------------- combine partials -> attn activations (bf16) ----------------
__global__ __launch_bounds__(128) void g_combine(
    const float* __restrict__ part, unsigned short* __restrict__ attn_bf) {
    int bk = blockIdx.x;
    int b = bk >> 3, kvh = bk & 7;
    const float* p0 = part + (size_t)bk * NCHUNK * 520;
    int tid = threadIdx.x;
    int g = tid >> 5, l32 = tid & 31;

    float M = -__builtin_inff();
#pragma unroll
    for (int c = 0; c < NCHUNK; ++c) {
        float lcv = p0[c * 520 + 4 + g];
        float mcv = p0[c * 520 + g];
        if (lcv > 0.f && mcv > M) M = mcv;
    }
    float L = 0.f;
    f32x4 acc = {0.f, 0.f, 0.f, 0.f};
#pragma unroll
    for (int c = 0; c < NCHUNK; ++c) {
        float lcv = p0[c * 520 + 4 + g];
        float mcv = p0[c * 520 + g];
        if (lcv > 0.f) {
            float wgt = expf(mcv - M);
            L += lcv * wgt;
            f32x4 a = *(const f32x4*)(p0 + c * 520 + 8 + g * DD + l32 * 4);
            acc += wgt * a;
        }
    }
    float inv = 1.0f / L;
    unsigned short* o = attn_bf + (((size_t)b * NH) + kvh * NG + g) * DD + l32 * 4;
#pragma unroll
    for (int r = 0; r < 4; ++r) o[r] = f2bf(acc[r] * inv);
}

// ---------------- o GEMM: barrier-free, wave-owned 16-col tiles ----------------
// grid (64, OSPLIT), block 256.
__global__ __launch_bounds__(256) void g_o(
    const unsigned short* __restrict__ attn_bf, const float* __restrict__ w_o,
    float* __restrict__ o_part) {
    int tid = threadIdx.x;
    int wave = tid >> 6, lane = tid & 63, l16 = lane & 15, kgrp = lane >> 4;
    int j0 = (blockIdx.x * 4 + wave) * 16;
    int ks = blockIdx.y;
    const int K = HID, Kslice = HID / OSPLIT;   // 256
    int kbeg = ks * Kslice;

    f32x4 acc0 = {0.f,0.f,0.f,0.f}, acc1 = {0.f,0.f,0.f,0.f};
    const unsigned short* ar0 = attn_bf + (size_t)l16 * K;
    const unsigned short* ar1 = attn_bf + (size_t)(16 + l16) * K;
    const float* wr = w_o + (size_t)(j0 + l16) * K;

#pragma unroll 4
    for (int k = kbeg; k < kbeg + Kslice; k += 32) {   // 8 iters
        int kk = k + kgrp * 8;
        bf16x8 a0 = *(const bf16x8*)(ar0 + kk);
        bf16x8 a1 = *(const bf16x8*)(ar1 + kk);
        f32x4 w0 = *(const f32x4*)(wr + kk), w1 = *(const f32x4*)(wr + kk + 4);
        u32x4 pw;
        pw[0] = pack_bf16(w0[0], w0[1]); pw[1] = pack_bf16(w0[2], w0[3]);
        pw[2] = pack_bf16(w1[0], w1[1]); pw[3] = pack_bf16(w1[2], w1[3]);
        bf16x8 bw = __builtin_bit_cast(bf16x8, pw);
        acc0 = __builtin_amdgcn_mfma_f32_16x16x32_bf16(a0, bw, acc0, 0, 0, 0);
        acc1 = __builtin_amdgcn_mfma_f32_16x16x32_bf16(a1, bw, acc1, 0, 0, 0);
    }
    float* dst = o_part + (size_t)ks * 32 * HID + j0 + l16;
#pragma unroll
    for (int r = 0; r < 4; ++r) {
        dst[(size_t)(kgrp * 4 + r) * HID] = acc0[r];
        dst[(size_t)(16 + kgrp * 4 + r) * HID] = acc1[r];
    }
}

// ---------------- reduce o partials -> out ----------------
__global__ __launch_bounds__(256) void g_reduce_o(
    const float* __restrict__ o_part, float* __restrict__ out) {
    int idx = blockIdx.x * 256 + threadIdx.x;   // 32768 f32x4 groups
    const f32x4* p = (const f32x4*)o_part;
    f32x4 s = p[idx];
#pragma unroll
    for (int k = 1; k < OSPLIT; ++k) s += p[idx + k * 32768];
    ((f32x4*)out)[idx] = s;
}

extern "C" void kernel_launch(void* const* d_in, const int* in_sizes, int n_in,
                              void* d_out, int out_size, void* d_ws, size_t ws_size,
                              hipStream_t stream) {
    const float* hs      = (const float*)d_in[0];
    const float* w_qkv   = (const float*)d_in[1];
    const float* w_o     = (const float*)d_in[2];
    const float* k_cache = (const float*)d_in[3];
    const float* v_cache = (const float*)d_in[4];
    const int*   positions = (const int*)d_in[5];
    float* out = (float*)d_out;
    float* wsf = (float*)d_ws;

    float* p_qkv_part = wsf + OFF_QKVP;
    float* p_q_rope   = wsf + OFF_QR;
    float* p_k_rope   = wsf + OFF_KR;
    float* p_vbuf     = wsf + OFF_VB;
    float* p_part     = wsf + OFF_PART;
    unsigned short* p_attn_bf = (unsigned short*)(wsf + OFF_ABF);
    float* p_o_part   = wsf + OFF_OPART;

    hipLaunchKernelGGL(g_qkv, dim3(96, QSPLIT), dim3(256), 0, stream,
                       hs, w_qkv, p_qkv_part);
    hipLaunchKernelGGL(g_rope, dim3(448), dim3(256), 0, stream,
                       p_qkv_part, positions, p_q_rope, p_k_rope, p_vbuf);
    hipLaunchKernelGGL(g_attn, dim3(256, NCHUNK), dim3(256), 0, stream,
                       k_cache, v_cache, p_q_rope, p_k_rope, p_vbuf, positions, p_part);
    hipLaunchKernelGGL(g_combine, dim3(NB * NKVH), dim3(128), 0, stream,
                       p_part, p_attn_bf);
    hipLaunchKernelGGL(g_o, dim3(64, OSPLIT), dim3(256), 0, stream,
                       p_attn_bf, w_o, p_o_part);
    hipLaunchKernelGGL(g_reduce_o, dim3(128), dim3(256), 0, stream, p_o_part, out);
}